// Round 4
// baseline (31.936 us; speedup 1.0000x reference)
//
#include <hip/hip_runtime.h>
#include <hip/hip_bf16.h>

#define NB 8
#define NS 4096
#define NH 1152
#define LEN 256
#define F4ROW (NH / 4)   // 288

typedef float vf4 __attribute__((ext_vector_type(4)));

// Single fused kernel. Block g = b*256 + seg owns one output row.
// Phase 1: self-service prep from L2-resident patch coords (32 KB/batch).
// Phase 2: balanced stream-sum. Cols 0..255 -> thread t (all waves equal);
// cols 256..287 -> round-robin across 8 half-wave groups (zero straggler).
__global__ __launch_bounds__(256) void gvp_fused(
        const float* __restrict__ hidden,
        const int* __restrict__ patch,
        float* __restrict__ out,
        float* __restrict__ maskout) {
    int g = blockIdx.x;                        // b*256 + seg
    int b = g >> 8;
    int myseg = g & (LEN - 1);
    int t = threadIdx.x;                       // 256 threads

    __shared__ __align__(16) int rows[NS];     // worst case; reused as reduce buf
    __shared__ int s_max[4];
    __shared__ int s_cnt;
    __shared__ int s_mult;
    if (t == 0) s_cnt = 0;

    // ---- Phase 1 ----
    const int2* p2 = (const int2*)(patch + (size_t)b * NS * 2);
    int pk[16];
    int m = 0;
    #pragma unroll
    for (int i = 0; i < 16; ++i) {
        int2 v = p2[t + 256 * i];
        int x = v.x < 0 ? 0 : v.x;
        int y = v.y < 0 ? 0 : v.y;
        pk[i] = x | (y << 16);
        m = max(m, x);
    }
    #pragma unroll
    for (int off = 32; off > 0; off >>= 1)
        m = max(m, __shfl_down(m, off, 64));
    if ((t & 63) == 0) s_max[t >> 6] = m;
    __syncthreads();
    if (t == 0)
        s_mult = (max(max(s_max[0], s_max[1]), max(s_max[2], s_max[3])) + 1) >> 2;
    __syncthreads();
    int mult = s_mult;

    #pragma unroll
    for (int i = 0; i < 16; ++i) {
        int x = pk[i] & 0xffff;
        int y = pk[i] >> 16;
        int seg = (x >> 2) + mult * (y >> 2);  // ref guarantees < LEN
        if (seg == myseg) {
            int pos = atomicAdd(&s_cnt, 1);
            rows[pos] = t + 256 * i;
        }
    }
    __syncthreads();
    int cnt = s_cnt;

    // ---- Phase 2: main columns (0..255), 8-row unroll ----
    const float* hb = hidden + (size_t)b * NS * NH;
    vf4 a0 = 0.f, a1 = 0.f;
    int r = 0;
    for (; r + 7 < cnt; r += 8) {
        const vf4* p0 = (const vf4*)(hb + (size_t)rows[r + 0] * NH);
        const vf4* p1 = (const vf4*)(hb + (size_t)rows[r + 1] * NH);
        const vf4* p2r = (const vf4*)(hb + (size_t)rows[r + 2] * NH);
        const vf4* p3 = (const vf4*)(hb + (size_t)rows[r + 3] * NH);
        const vf4* p4 = (const vf4*)(hb + (size_t)rows[r + 4] * NH);
        const vf4* p5 = (const vf4*)(hb + (size_t)rows[r + 5] * NH);
        const vf4* p6 = (const vf4*)(hb + (size_t)rows[r + 6] * NH);
        const vf4* p7 = (const vf4*)(hb + (size_t)rows[r + 7] * NH);
        vf4 v0 = p0[t], v1 = p1[t], v2 = p2r[t], v3 = p3[t];
        vf4 v4 = p4[t], v5 = p5[t], v6 = p6[t], v7 = p7[t];
        v0 += v1; v2 += v3; v4 += v5; v6 += v7;
        v0 += v2; v4 += v6;
        a0 += v0; a1 += v4;
    }
    for (; r < cnt; ++r) {
        const vf4* p0 = (const vf4*)(hb + (size_t)rows[r] * NH);
        a0 += p0[t];
    }
    a0 += a1;

    // ---- Phase 2: tail columns (256..287), balanced round-robin ----
    int l = t & 31;
    int grp = t >> 5;                          // 8 half-wave groups
    vf4 a2 = 0.f;
    for (int r2 = grp; r2 < cnt; r2 += 8) {
        const vf4* p = (const vf4*)(hb + (size_t)rows[r2] * NH);
        a2 += p[256 + l];
    }
    __syncthreads();                           // all rows[] reads done
    vf4* red = (vf4*)rows;                     // reuse LDS (16 KB >= 4 KB)
    red[t] = a2;
    __syncthreads();

    const float scale = 2.1213203435596424f;   // sqrt(1152) / 16
    vf4* og = (vf4*)(out + (size_t)g * NH);
    og[t] = a0 * scale;
    if (t < 32) {
        vf4 s = 0.f;
        #pragma unroll
        for (int j = 0; j < 8; ++j) s += red[j * 32 + t];
        og[256 + t] = s * scale;
    }
    if (t == 0) maskout[g] = (cnt > 0) ? 1.0f : 0.0f;
}

extern "C" void kernel_launch(void* const* d_in, const int* in_sizes, int n_in,
                              void* d_out, int out_size, void* d_ws, size_t ws_size,
                              hipStream_t stream) {
    const float* hidden = (const float*)d_in[0];
    const int*   patch  = (const int*)d_in[1];
    // d_in[2] (padding_positions) unused: S != LENGTH branch.
    float* out = (float*)d_out;
    float* maskout = out + (size_t)NB * LEN * NH;   // tuple: pooled then mask

    gvp_fused<<<NB * LEN, 256, 0, stream>>>(hidden, patch, out, maskout);
}